// Round 6
// baseline (4067.024 us; speedup 1.0000x reference)
//
#include <hip/hip_runtime.h>
#include <cmath>

#define HID 150
#define FOURH 600
#define BATCH 64
#define TLEN 2048
#define NKS 5  // 32-wide k-slices over k padded 150->160

typedef __attribute__((ext_vector_type(2))) _Float16 half2_t;

#if defined(__has_builtin)
#if __has_builtin(__builtin_amdgcn_fdot2)
#define FDOT2(a, b, c) __builtin_amdgcn_fdot2((a), (b), (c), false)
#endif
#endif
#ifndef FDOT2
__device__ __forceinline__ float fdot2_fb(half2_t a, half2_t b, float c) {
    return c + (float)a.x * (float)b.x + (float)a.y * (float)b.y;
}
#define FDOT2(a, b, c) fdot2_fb((a), (b), (c))
#endif

__device__ __forceinline__ float sigmoidf_(float x) {
    return 1.0f / (1.0f + __expf(-x));
}
__device__ __forceinline__ float tanhf_(float x) {
    return 1.0f - 2.0f / (__expf(2.0f * x) + 1.0f);
}

// x_proj[b, i, c] = bias[c] + sum_k X[b, t0+i, k] * Wx[k, c]   (f32)
__global__ __launch_bounds__(640, 2) void xproj_gemm(
    const float* __restrict__ X,     // [BATCH, TLEN, 150]
    const float* __restrict__ Wx,    // [150, 600]
    const float* __restrict__ bias,  // [600]
    float* __restrict__ xp,          // [BATCH, C, 600]
    int t0, int C)
{
    const int blocks_per_batch = C / 32;
    const int b  = blockIdx.x / blocks_per_batch;
    const int i0 = (blockIdx.x % blocks_per_batch) * 32;
    const float* Xbase = X + ((size_t)(b * TLEN + t0 + i0)) * HID;

    __shared__ __align__(16) float xt[150 * 36];
    const int tid = threadIdx.x;
    for (int i = tid; i < 32 * HID; i += 640) {
        int r = i / HID, k = i % HID;
        xt[k * 36 + r] = Xbase[(size_t)r * HID + k];
    }
    __syncthreads();

    if (tid < FOURH) {
        float acc[32];
        #pragma unroll
        for (int r = 0; r < 32; ++r) acc[r] = 0.f;
        for (int k = 0; k < HID; ++k) {
            float w = Wx[(size_t)k * FOURH + tid];
            #pragma unroll
            for (int r4 = 0; r4 < 8; ++r4) {
                float4 xv = *(const float4*)&xt[k * 36 + r4 * 4];
                acc[r4*4+0] += xv.x * w;
                acc[r4*4+1] += xv.y * w;
                acc[r4*4+2] += xv.z * w;
                acc[r4*4+3] += xv.w * w;
            }
        }
        float bv = bias[tid];
        float* o = xp + ((size_t)b * C + i0) * FOURH + tid;
        #pragma unroll
        for (int r = 0; r < 32; ++r) o[(size_t)r * FOURH] = acc[r] + bv;
    }
}

// Pack Wh (f32 [150,600]) into per-thread-sliced half2 layout:
// whp[layer][ks*9600 + (g*16+p)*150 + j] = (Wh[32ks+2p][g*150+j], Wh[32ks+2p+1][...])
__global__ void pack_wh(const float* __restrict__ Wh0, const float* __restrict__ Wh1,
                        half2_t* __restrict__ whp) {
    int idx = blockIdx.x * 256 + threadIdx.x;
    if (idx >= 2 * 48000) return;
    int layer = idx / 48000, r = idx - layer * 48000;
    int j = r % HID, t = r / HID;       // t = (ks*4+g)*16+p
    int p = t & 15, gks = t >> 4;
    int g = gks & 3, ks = gks >> 2;
    const float* Wh = layer ? Wh1 : Wh0;
    int k0 = ks * 32 + 2 * p;
    float a  = (k0 < HID)     ? Wh[(size_t)k0 * FOURH + g * HID + j]       : 0.f;
    float bb = (k0 + 1 < HID) ? Wh[(size_t)(k0 + 1) * FOURH + g * HID + j] : 0.f;
    half2_t h; h.x = (_Float16)a; h.y = (_Float16)bb;
    whp[idx] = h;
}

// ---- AGPR-resident weight machinery ----
// The allocator rematerialized/spilled plain VGPR weight arrays through 4
// prior countermeasures (journal r1-r5: step time pinned at ~0.92us = L2
// weight re-fetch floor). Pin each weight into the accumulator file with
// explicit v_accvgpr_write; read back per use. 64 AGPR + ~70 VGPR fits the
// 170-reg budget at 3 waves/EU with zero pressure.
#define AWRITE(dst, G, P) { half2_t _t = Wj[((G) * 16 + (P)) * HID]; \
    float _tf = __builtin_bit_cast(float, _t); \
    asm volatile("v_accvgpr_write_b32 %0, %1" : "=a"(dst[(P)]) : "v"(_tf)); }
#define AW16(dst, G) AWRITE(dst,G,0) AWRITE(dst,G,1) AWRITE(dst,G,2) AWRITE(dst,G,3) \
  AWRITE(dst,G,4) AWRITE(dst,G,5) AWRITE(dst,G,6) AWRITE(dst,G,7) \
  AWRITE(dst,G,8) AWRITE(dst,G,9) AWRITE(dst,G,10) AWRITE(dst,G,11) \
  AWRITE(dst,G,12) AWRITE(dst,G,13) AWRITE(dst,G,14) AWRITE(dst,G,15)

// Read AGPR weight -> fdot2 against h pair.
#define ADOT(acc, arr, I, hh) { float _wf; \
    asm volatile("v_accvgpr_read_b32 %0, %1" : "=v"(_wf) : "a"(arr[(I)])); \
    acc = FDOT2((hh), __builtin_bit_cast(half2_t, _wf), acc); }

// One quarter of the k-slice: 4 half2 of h (16B LDS read), 16 AGPR-read+fdot2.
#define DOTQ(Q) { \
  float4 hv = *(const float4*)(const void*)&h16[ks * 32 + (Q) * 8]; \
  half2_t h0 = __builtin_bit_cast(half2_t, hv.x); \
  half2_t h1 = __builtin_bit_cast(half2_t, hv.y); \
  half2_t h2 = __builtin_bit_cast(half2_t, hv.z); \
  half2_t h3 = __builtin_bit_cast(half2_t, hv.w); \
  ADOT(a0, aw0, (Q)*4+0, h0) ADOT(a0, aw0, (Q)*4+1, h1) \
  ADOT(a0, aw0, (Q)*4+2, h2) ADOT(a0, aw0, (Q)*4+3, h3) \
  ADOT(a1, aw1, (Q)*4+0, h0) ADOT(a1, aw1, (Q)*4+1, h1) \
  ADOT(a1, aw1, (Q)*4+2, h2) ADOT(a1, aw1, (Q)*4+3, h3) \
  ADOT(a2, aw2, (Q)*4+0, h0) ADOT(a2, aw2, (Q)*4+1, h1) \
  ADOT(a2, aw2, (Q)*4+2, h2) ADOT(a2, aw2, (Q)*4+3, h3) \
  ADOT(a3, aw3, (Q)*4+0, h0) ADOT(a3, aw3, (Q)*4+1, h1) \
  ADOT(a3, aw3, (Q)*4+2, h2) ADOT(a3, aw3, (Q)*4+3, h3) }

// Dual-part recurrence: WGs 0-63 = part A, WGs 64-127 = part B (other layer,
// previous chunk). 768 threads; thread (j, ks) owns all 4 gates of unit j
// over a 32-wide k-slice as 64 AGPR-pinned packed half2 weights.
__global__ __launch_bounds__(768)
__attribute__((amdgpu_waves_per_eu(3, 3)))
void lstm_recur2(const float* __restrict__ xpA, const half2_t* __restrict__ whpA,
                 float* __restrict__ stA, int t0A,
                 const float* __restrict__ xpB, const half2_t* __restrict__ whpB,
                 float* __restrict__ stB, int t0B,
                 float* __restrict__ out, int C)
{
    const int part = blockIdx.x >> 6;
    const int b = blockIdx.x & 63;
    const int tid = threadIdx.x;
    const int tidc = (tid < 750) ? tid : 749;   // clamp: unconditional loads
    const int ks = tidc / HID;       // 0..4
    const int j  = tidc - ks * HID;  // 0..149

    const float*   xp    = part ? xpB  : xpA;
    const half2_t* whp   = part ? whpB : whpA;
    float*         state = part ? stB  : stA;
    const int      t0    = part ? t0B  : t0A;

    __shared__ __align__(16) _Float16 h16[160];      // h as f16, tail zero
    __shared__ __align__(16) float part_s[NKS][4][152];

    float aw0[16], aw1[16], aw2[16], aw3[16];  // AGPR-pinned weights
    {
        const half2_t* Wj = whp + (size_t)ks * 9600 + j;
        AW16(aw0, 0) AW16(aw1, 1) AW16(aw2, 2) AW16(aw3, 3)
    }

    float cst = 0.f;
    if (tid < 160) {
        float hv = 0.f;
        if (t0 != 0 && tid < HID) {
            cst = state[b * 300 + tid];
            hv  = state[b * 300 + HID + tid];
        }
        h16[tid] = (_Float16)hv;
    }
    __syncthreads();

    const float* xpb = xp + (size_t)b * C * FOURH;
    float* outb = out + ((size_t)b * TLEN + t0) * HID;

    float xn0 = 0.f, xn1 = 0.f, xn2 = 0.f, xn3 = 0.f;
    if (tid < HID) {
        xn0 = xpb[tid];
        xn1 = xpb[HID + tid];
        xn2 = xpb[2 * HID + tid];
        xn3 = xpb[3 * HID + tid];
    }

    for (int i = 0; i < C; ++i) {
        // ---- Stage A: 64 AGPR-read + v_dot2 per thread (750 threads) ----
        if (tid < 750) {
            float a0 = 0.f, a1 = 0.f, a2 = 0.f, a3 = 0.f;
            DOTQ(0) DOTQ(1) DOTQ(2) DOTQ(3)
            part_s[ks][0][j] = a0;
            part_s[ks][1][j] = a1;
            part_s[ks][2][j] = a2;
            part_s[ks][3][j] = a3;
        }
        __syncthreads();

        // ---- Stage B: reduce, activate, update c/h (150 threads) ----
        if (tid < HID) {
            float p0 = xn0, p1 = xn1, p2 = xn2, p3 = xn3;
            if (i + 1 < C) {
                const float* p = &xpb[(size_t)(i + 1) * FOURH];
                xn0 = p[tid];
                xn1 = p[HID + tid];
                xn2 = p[2 * HID + tid];
                xn3 = p[3 * HID + tid];
            }
            float z0 = p0, z1 = p1, z2 = p2, z3 = p3;
            #pragma unroll
            for (int s = 0; s < NKS; ++s) {
                z0 += part_s[s][0][tid];
                z1 += part_s[s][1][tid];
                z2 += part_s[s][2][tid];
                z3 += part_s[s][3][tid];
            }
            float ig = sigmoidf_(z0);
            float fg = sigmoidf_(z1);
            float gg = tanhf_(z2);
            float og = sigmoidf_(z3);
            cst = fg * cst + ig * gg;
            float hn = og * tanhf_(cst);
            h16[tid] = (_Float16)hn;
            outb[(size_t)i * HID + tid] = hn;
        }
        __syncthreads();
    }

    if (tid < HID) {
        state[b * 300 + tid] = cst;
        state[b * 300 + HID + tid] = (float)h16[tid];
    }
}

extern "C" void kernel_launch(void* const* d_in, const int* in_sizes, int n_in,
                              void* d_out, int out_size, void* d_ws, size_t ws_size,
                              hipStream_t stream) {
    const float* xs  = (const float*)d_in[0];
    const float* Wx0 = (const float*)d_in[1];
    const float* Wh0 = (const float*)d_in[2];
    const float* b0  = (const float*)d_in[3];
    const float* Wx1 = (const float*)d_in[4];
    const float* Wh1 = (const float*)d_in[5];
    const float* b1  = (const float*)d_in[6];
    float* out = (float*)d_out;

    // Chunk size: two xp buffers + packed weights + states must fit in ws.
    int C = 256;
    while (C > 32) {
        size_t need = 2 * (size_t)BATCH * C * FOURH * 4    // xp0, xp1
                    + 2 * 48000 * 4                        // whp (half2 = 4B)
                    + 2 * (size_t)BATCH * 300 * 4;         // states
        if (need <= ws_size) break;
        C >>= 1;
    }
    char* w = (char*)d_ws;
    float* xp0 = (float*)w;                 w += (size_t)BATCH * C * FOURH * 4;
    float* xp1 = (float*)w;                 w += (size_t)BATCH * C * FOURH * 4;
    half2_t* whp0 = (half2_t*)w;            w += 48000 * 4;
    half2_t* whp1 = (half2_t*)w;            w += 48000 * 4;
    float* st0 = (float*)w;                 w += (size_t)BATCH * 300 * 4;
    float* st1 = (float*)w;

    pack_wh<<<dim3((2 * 48000 + 255) / 256), dim3(256), 0, stream>>>(Wh0, Wh1, whp0);

    const int nchunk = TLEN / C;
    const int gpb = C / 32;  // xproj blocks per batch

    // Software pipeline: slot s runs L0 chunk s and L1 chunk s-1 concurrently.
    for (int s = 0; s <= nchunk; ++s) {
        const bool hasA = (s < nchunk);   // L0 chunk s
        const bool hasB = (s >= 1);       // L1 chunk s-1
        if (hasA)
            xproj_gemm<<<dim3(BATCH * gpb), dim3(640), 0, stream>>>(
                xs, Wx0, b0, xp0, s * C, C);
        if (hasB)
            xproj_gemm<<<dim3(BATCH * gpb), dim3(640), 0, stream>>>(
                out, Wx1, b1, xp1, (s - 1) * C, C);
        if (hasA && hasB)
            lstm_recur2<<<dim3(128), dim3(768), 0, stream>>>(
                xp0, whp0, st0, s * C, xp1, whp1, st1, (s - 1) * C, out, C);
        else if (hasA)
            lstm_recur2<<<dim3(64), dim3(768), 0, stream>>>(
                xp0, whp0, st0, s * C, xp0, whp0, st0, 0, out, C);
        else
            lstm_recur2<<<dim3(64), dim3(768), 0, stream>>>(
                xp1, whp1, st1, (s - 1) * C, xp1, whp1, st1, 0, out, C);
    }
}